// Round 9
// baseline (759.658 us; speedup 1.0000x reference)
//
#include <hip/hip_runtime.h>

// (V, D, H, L, E) = (50000, 128, 128, 4, 160000)
#define V_NODES 50000
#define NEDGE   160000
#define NSEG    (8 * V_NODES)          // 400000 (g,node) segments
#define NPOS    224                    // owned sorted positions per block
#define NTOT    256                    // computed positions (owned + 32 halo)
#define NBLK_FUSED 715                 // ceil(160000/224)
#define NBLK_SCAN 782                  // ceil(400000/512)

typedef __bf16 bf16;
typedef __attribute__((ext_vector_type(8))) __bf16 bf16x8;
typedef __attribute__((ext_vector_type(4))) __bf16 bf16x4;
typedef __attribute__((ext_vector_type(4))) float  f32x4;

__device__ __forceinline__ int clampV(int n) {
  unsigned u = (unsigned)n;
  return (int)(u < (unsigned)V_NODES ? u : (unsigned)(V_NODES - 1));
}

__device__ __forceinline__ bf16x8 bzero8() {
  bf16x8 z;
  #pragma unroll
  for (int i = 0; i < 8; ++i) z[i] = (bf16)0.f;
  return z;
}

// ---------------- combined prep: emb->bf16, W1/W2 transpose, histogram -----
// blocks [0,6250): emb cvt; [6250,7786): weights; [7786,10286): hist (int2,
// both endpoints -> counts for g=2l and g=2l+1). counts pre-zeroed by memset.

__global__ __launch_bounds__(256) void prep_all_k(
    const float* __restrict__ emb, const float* __restrict__ W1,
    const float* __restrict__ W2,
    const int* __restrict__ a0, const int* __restrict__ a1,
    const int* __restrict__ a2, const int* __restrict__ a3,
    bf16* __restrict__ embB, bf16* __restrict__ w1t, bf16* __restrict__ w2t,
    int* __restrict__ counts) {
  const int b = blockIdx.x, t = threadIdx.x;
  if (b < 6250) {
    int i = b * 256 + t;
    float4 v = ((const float4*)emb)[i];
    bf16x4 o = {(bf16)v.x, (bf16)v.y, (bf16)v.z, (bf16)v.w};
    *(bf16x4*)(embB + (size_t)i * 4) = o;
  } else if (b < 7786) {
    int idx = (b - 6250) * 256 + t;
    if (idx < 262144) {
      int n = idx & 127, k = (idx >> 7) & 255, g = idx >> 15;
      w1t[(((g << 7) + n) << 8) + k] = (bf16)W1[idx];
    } else {
      int j = idx - 262144;
      int n = j & 127, k = (j >> 7) & 127, g = j >> 14;
      w2t[(((g << 7) + n) << 7) + k] = (bf16)W2[j];
    }
  } else {
    int j = b - 7786;
    int l = j / 625;
    int e = (j % 625) * 256 + t;
    const int* adj = (l == 0) ? a0 : (l == 1) ? a1 : (l == 2) ? a2 : a3;
    int2 pr = ((const int2*)adj)[e];
    atomicAdd(&counts[(2 * l) * V_NODES + clampV(pr.x)], 1);
    atomicAdd(&counts[(2 * l + 1) * V_NODES + clampV(pr.y)], 1);
  }
}

// ---------------- scan (block-local) + block-sum scan ----------------------

__global__ __launch_bounds__(256) void scan_a_k(const int* __restrict__ counts,
                                                int* __restrict__ offs,
                                                int* __restrict__ bsums) {
  __shared__ int sh[256];
  int t = threadIdx.x, base = blockIdx.x * 512;
  int e0 = base + 2 * t, e1 = e0 + 1;
  int a = (e0 < NSEG) ? counts[e0] : 0;
  int b = (e1 < NSEG) ? counts[e1] : 0;
  int s = a + b;
  sh[t] = s;
  __syncthreads();
  #pragma unroll
  for (int d = 1; d < 256; d <<= 1) {
    int v = (t >= d) ? sh[t - d] : 0;
    __syncthreads();
    sh[t] += v;
    __syncthreads();
  }
  int excl = sh[t] - s;
  if (e0 < NSEG) offs[e0] = excl;
  if (e1 < NSEG) offs[e1] = excl + a;
  if (t == 255) bsums[blockIdx.x] = sh[255];
}

__global__ __launch_bounds__(256) void scan_b_k(int* __restrict__ bsums) {
  __shared__ int sh[256];
  int t = threadIdx.x;
  int v[4]; int s = 0;
  #pragma unroll
  for (int k = 0; k < 4; ++k) {
    int i = t * 4 + k;
    v[k] = (i < NBLK_SCAN) ? bsums[i] : 0;
    s += v[k];
  }
  sh[t] = s;
  __syncthreads();
  #pragma unroll
  for (int d = 1; d < 256; d <<= 1) {
    int x = (t >= d) ? sh[t - d] : 0;
    __syncthreads();
    sh[t] += x;
    __syncthreads();
  }
  int run = sh[t] - s;
  #pragma unroll
  for (int k = 0; k < 4; ++k) {
    int i = t * 4 + k;
    if (i < NBLK_SCAN) bsums[i] = run;
    run += v[k];
  }
}

// ---------------- scatter (scan_c folded in; both endpoints per edge) ------

__global__ __launch_bounds__(256) void scatter2_k(
    const int* __restrict__ a0, const int* __restrict__ a1,
    const int* __restrict__ a2, const int* __restrict__ a3,
    const int* __restrict__ offs, const int* __restrict__ bsums,
    int* __restrict__ cursor, int* __restrict__ ids) {
  int e = blockIdx.x * 256 + threadIdx.x;
  int l = blockIdx.y;
  const int* adj = (l == 0) ? a0 : (l == 1) ? a1 : (l == 2) ? a2 : a3;
  int2 pr = ((const int2*)adj)[e];
  int s0 = (2 * l) * V_NODES + clampV(pr.x);
  int s1 = (2 * l + 1) * V_NODES + clampV(pr.y);
  int p0 = offs[s0] + bsums[s0 >> 9] + atomicAdd(&cursor[s0], 1);
  ids[p0] = e;
  int p1 = offs[s1] + bsums[s1 >> 9] + atomicAdd(&cursor[s1], 1);
  ids[p1] = e;
}

// ---------------- fused GEMM1 + segmented aggregation (v3: dbuf gathers) ---
// Same math as round 8 (proven); phase-1 gathers now explicitly double-
// buffered (b0/b1) with sched_barrier so the 8 loads of tile t+1 issue as a
// batch before MFMA(t) -> serial-latency pathology removed. launch_bounds
// (512,3) lets VGPR grow to ~150 so both buffers + wA stay resident.

__global__ __launch_bounds__(512, 3) void fused_k(
    const bf16* __restrict__ embB,
    const int* __restrict__ a0, const int* __restrict__ a1,
    const int* __restrict__ a2, const int* __restrict__ a3,
    const bf16* __restrict__ w1t,
    const int* __restrict__ ids,
    bf16* __restrict__ Hagg) {

  __shared__ __attribute__((aligned(16))) bf16 h_lds[NTOT * 128]; // 65536 B
  __shared__ int2 pairs_lds[NTOT];
  __shared__ int  nds_lds[NTOT];
  __shared__ int  starts_lds[NPOS];
  __shared__ int  cnt_lds;
  __shared__ int  prev_lds;

  const int tid = threadIdx.x;
  const int g  = blockIdx.y;
  const int l = g >> 1, ep = g & 1;
  const int* __restrict__ adj = (l == 0) ? a0 : (l == 1) ? a1 : (l == 2) ? a2 : a3;
  const int bl = blockIdx.x;
  const int p0 = g * NEDGE + bl * NPOS;
  const int rem = NEDGE - bl * NPOS;         // >= 64 by grid construction
  const int ntv = rem < NTOT ? rem : NTOT;
  const int npo = rem < NPOS ? rem : NPOS;

  if (tid == 0) {
    cnt_lds = 0;
    prev_lds = (bl > 0) ? clampV(adj[2 * ids[p0 - 1] + ep]) : -2;
  }
  if (tid < NTOT) {
    int2 pr = {0, 0};
    int nd = -1;
    if (tid < ntv) {
      int e = ids[p0 + tid];
      pr = ((const int2*)adj)[e];
      pr.x = clampV(pr.x); pr.y = clampV(pr.y);
      nd = ep ? pr.y : pr.x;
    }
    pairs_lds[tid] = pr;
    nds_lds[tid] = nd;
  }

  const int w = tid >> 6, lane = tid & 63;
  const int dq = w & 3, sub = w >> 2;        // dim-quarter, position-sub
  const int l15 = lane & 15, q = lane >> 4;

  // W1^T A-fragments in registers: dims dq*32 + mb*16 + l15, k = kb*32+q*8
  bf16x8 wA[2][8];
  const bf16* w1row = w1t + ((size_t)(g * 128 + dq * 32)) * 256;
  #pragma unroll
  for (int mb = 0; mb < 2; ++mb)
    #pragma unroll
    for (int kb = 0; kb < 8; ++kb)
      wA[mb][kb] = *(const bf16x8*)(w1row + (mb * 16 + l15) * 256 + kb * 32 + q * 8);

  __syncthreads();   // staging visible

  // segment-start detection
  if (tid < npo) {
    int nd = nds_lds[tid];
    int pv = tid ? nds_lds[tid - 1] : prev_lds;
    if (nd != pv) starts_lds[atomicAdd(&cnt_lds, 1)] = tid;
  }

  // ---- phase 1: double-buffered gather + MFMA ----
  bf16x8 b0[8], b1[8];
  {
    int2 pr = pairs_lds[sub * 16 + l15];
    #pragma unroll
    for (int kb = 0; kb < 8; ++kb) {
      const int node = (kb < 4) ? pr.x : pr.y;
      b0[kb] = *(const bf16x8*)(embB + (size_t)node * 128 + ((kb * 32 + q * 8) & 127));
    }
  }
  #pragma unroll
  for (int t = 0; t < 8; ++t) {
    if (t < 7) {
      int2 pr = pairs_lds[(t + 1) * 32 + sub * 16 + l15];
      #pragma unroll
      for (int kb = 0; kb < 8; ++kb) {
        const int node = (kb < 4) ? pr.x : pr.y;
        bf16x8 v = *(const bf16x8*)(embB + (size_t)node * 128 + ((kb * 32 + q * 8) & 127));
        if (t & 1) b0[kb] = v; else b1[kb] = v;
      }
    }
    __builtin_amdgcn_sched_barrier(0);   // keep prefetch loads before MFMA
    f32x4 acc[2] = {};
    #pragma unroll
    for (int kb = 0; kb < 8; ++kb) {
      bf16x8 bc = (t & 1) ? b1[kb] : b0[kb];
      #pragma unroll
      for (int mb = 0; mb < 2; ++mb)
        acc[mb] = __builtin_amdgcn_mfma_f32_16x16x32_bf16(wA[mb][kb], bc, acc[mb], 0, 0, 0);
    }
    const int j = t * 32 + sub * 16 + l15;
    #pragma unroll
    for (int mb = 0; mb < 2; ++mb) {
      const int c = (dq << 3) | (mb << 2) | q;
      bf16x4 o = {(bf16)fmaxf(acc[mb][0], 0.f), (bf16)fmaxf(acc[mb][1], 0.f),
                  (bf16)fmaxf(acc[mb][2], 0.f), (bf16)fmaxf(acc[mb][3], 0.f)};
      *(bf16x4*)(&h_lds[j * 128 + ((c ^ (j & 15)) << 2)]) = o;
    }
  }
  __syncthreads();   // h + starts visible

  // ---- phase 2: 8-way wave-parallel segment reduction ----
  const int ncnt = cnt_lds;
  const int ch = lane >> 1;
  const int hw = (lane & 1) << 1;
  bf16* __restrict__ HaggG = Hagg + (size_t)g * V_NODES * 128;
  for (int i = w; i < ncnt; i += 8) {
    int j = starts_lds[i];
    const int node = nds_lds[j];
    float sx = 0.f, sy = 0.f;
    do {
      unsigned u = *(const unsigned*)(&h_lds[j * 128 + ((ch ^ (j & 15)) << 2) + hw]);
      sx += (float)__builtin_bit_cast(bf16, (unsigned short)u);
      sy += (float)__builtin_bit_cast(bf16, (unsigned short)(u >> 16));
      ++j;
    } while (j < ntv && nds_lds[j] == node);
    bf16 plo = (bf16)sx, phi = (bf16)sy;
    unsigned pu = (unsigned)__builtin_bit_cast(unsigned short, plo)
                | ((unsigned)__builtin_bit_cast(unsigned short, phi) << 16);
    *(unsigned*)(HaggG + (size_t)node * 128 + lane * 2) = pu;
  }
}

// ---------------- final GEMM: out = relu(sum_g Hagg_g @ W2_g) --------------
// counts==0 rows are never written by fused_k (hold 0xAA poison) -> zero-mask.

__global__ __launch_bounds__(256) void gemm2_k(const bf16* __restrict__ Hagg,
                                               const bf16* __restrict__ w2t,
                                               const int* __restrict__ counts,
                                               float* __restrict__ out) {
  const int tid = threadIdx.x, wv = tid >> 6, lane = tid & 63;
  const int l15 = lane & 15, q = lane >> 4;
  const int v0 = blockIdx.x * 64;
  const int vr = v0 + wv * 16 + l15;
  const int vc = vr < V_NODES ? vr : V_NODES - 1;

  f32x4 acc[8] = {};
  for (int g = 0; g < 8; ++g) {
    const int cnt = counts[g * V_NODES + vc];
    const bf16* Ha = Hagg + ((size_t)g * V_NODES + vc) * 128;
    const bf16* Wb = w2t + (size_t)g * 128 * 128;
    #pragma unroll
    for (int kb = 0; kb < 4; ++kb) {
      bf16x8 a = *(const bf16x8*)(Ha + kb * 32 + q * 8);
      if (cnt == 0) a = bzero8();
      #pragma unroll
      for (int nb = 0; nb < 8; ++nb) {
        bf16x8 b = *(const bf16x8*)(Wb + (nb * 16 + l15) * 128 + kb * 32 + q * 8);
        acc[nb] = __builtin_amdgcn_mfma_f32_16x16x32_bf16(a, b, acc[nb], 0, 0, 0);
      }
    }
  }

  const int row = v0 + wv * 16 + q * 4;
  #pragma unroll
  for (int r = 0; r < 4; ++r) {
    if (row + r < V_NODES) {
      #pragma unroll
      for (int nb = 0; nb < 8; ++nb)
        out[(size_t)(row + r) * 128 + nb * 16 + l15] = fmaxf(acc[nb][r], 0.f);
    }
  }
}

// ---------------- fallback path (round-4, proven) --------------------------

__global__ __launch_bounds__(256) void prep_emb_k(const float* __restrict__ in,
                                                  bf16* __restrict__ out) {
  int i = blockIdx.x * 256 + threadIdx.x;
  float4 v = ((const float4*)in)[i];
  bf16x4 o = {(bf16)v.x, (bf16)v.y, (bf16)v.z, (bf16)v.w};
  *(bf16x4*)(out + (size_t)i * 4) = o;
}

__global__ __launch_bounds__(256) void prep_w_k(const float* __restrict__ W1,
                                                const float* __restrict__ W2,
                                                bf16* __restrict__ w1t,
                                                bf16* __restrict__ w2t) {
  int idx = blockIdx.x * 256 + threadIdx.x;
  if (idx < 262144) {
    int n = idx & 127, k = (idx >> 7) & 255, g = idx >> 15;
    w1t[(((g << 7) + n) << 8) + k] = (bf16)W1[idx];
  } else {
    int j = idx - 262144;
    int n = j & 127, k = (j >> 7) & 127, g = j >> 14;
    w2t[(((g << 7) + n) << 7) + k] = (bf16)W2[j];
  }
}

__global__ __launch_bounds__(256) void relu_k(float* __restrict__ out) {
  int i = blockIdx.x * 256 + threadIdx.x;
  float4 v = ((float4*)out)[i];
  v.x = fmaxf(v.x, 0.f); v.y = fmaxf(v.y, 0.f);
  v.z = fmaxf(v.z, 0.f); v.w = fmaxf(v.w, 0.f);
  ((float4*)out)[i] = v;
}

__global__ __launch_bounds__(256) void edge_k(
    const bf16* __restrict__ embB,
    const int* __restrict__ a0, const int* __restrict__ a1,
    const int* __restrict__ a2, const int* __restrict__ a3,
    const bf16* __restrict__ w1t, const bf16* __restrict__ w2t,
    float* __restrict__ out) {

  __shared__ __attribute__((aligned(16))) bf16 w1_lds[128 * 256];
  __shared__ __attribute__((aligned(16))) bf16 h_lds[64 * 128];

  const int tid = threadIdx.x;
  const int g  = blockIdx.x >> 6;
  const int bs = blockIdx.x & 63;
  const int l = g >> 1, ep = g & 1;
  const int* __restrict__ adj = (l == 0) ? a0 : (l == 1) ? a1 : (l == 2) ? a2 : a3;

  {
    const uint4* w1g = (const uint4*)(w1t + (size_t)g * 128 * 256);
    #pragma unroll
    for (int i = 0; i < 16; ++i) {
      int j = i * 256 + tid;
      int n = j >> 5, c = j & 31;
      *(uint4*)(&w1_lds[n * 256 + ((c ^ (n & 7)) << 3)]) = w1g[j];
    }
  }
  __syncthreads();

  const int w    = tid >> 6;
  const int lane = tid & 63;
  const int wr = w >> 1, wc = w & 1;
  const int l15 = lane & 15, q = lane >> 4;
  const bf16* __restrict__ w2g = w2t + (size_t)g * 128 * 128;

  for (int t = bs; t < 2500; t += 64) {
    const int ebase = t * 64;
    int2 pr0 = ((const int2*)adj)[ebase + 32 * wr + l15];
    int2 pr1 = ((const int2*)adj)[ebase + 32 * wr + 16 + l15];
    pr0.x = clampV(pr0.x); pr0.y = clampV(pr0.y);
    pr1.x = clampV(pr1.x); pr1.y = clampV(pr1.y);

    f32x4 acc[2][4] = {};
    #pragma unroll
    for (int kb = 0; kb < 8; ++kb) {
      const int k = kb * 32 + q * 8;
      const int klo = k & 127;
      const int n0 = (kb < 4) ? pr0.x : pr0.y;
      const int n1 = (kb < 4) ? pr1.x : pr1.y;
      bf16x8 a[2], b[4];
      a[0] = *(const bf16x8*)(embB + (size_t)n0 * 128 + klo);
      a[1] = *(const bf16x8*)(embB + (size_t)n1 * 128 + klo);
      const int csw = ((kb << 2) + q);
      #pragma unroll
      for (int nt = 0; nt < 4; ++nt) {
        int n = 64 * wc + 16 * nt + l15;
        b[nt] = *(const bf16x8*)(&w1_lds[n * 256 + ((csw ^ (l15 & 7)) << 3)]);
      }
      #pragma unroll
      for (int mt = 0; mt < 2; ++mt)
        #pragma unroll
        for (int nt = 0; nt < 4; ++nt)
          acc[mt][nt] = __builtin_amdgcn_mfma_f32_16x16x32_bf16(a[mt], b[nt], acc[mt][nt], 0, 0, 0);
    }

    __syncthreads();
    #pragma unroll
    for (int mt = 0; mt < 2; ++mt)
      #pragma unroll
      for (int nt = 0; nt < 4; ++nt)
        #pragma unroll
        for (int r = 0; r < 4; ++r) {
          float v = acc[mt][nt][r];
          v = v > 0.f ? v : 0.f;
          int row = 32 * wr + 16 * mt + 4 * q + r;
          int col = 64 * wc + 16 * nt + l15;
          int c = col >> 3;
          h_lds[row * 128 + (((c ^ (row & 7)) << 3) | (col & 7))] = (bf16)v;
        }
    __syncthreads();

    f32x4 acc2[2][4] = {};
    #pragma unroll
    for (int kb = 0; kb < 4; ++kb) {
      const int k = kb * 32 + q * 8;
      const int csw = (kb << 2) + q;
      bf16x8 a[2], b[4];
      #pragma unroll
      for (int mt = 0; mt < 2; ++mt) {
        int row = 32 * wr + 16 * mt + l15;
        a[mt] = *(const bf16x8*)(&h_lds[row * 128 + ((csw ^ (row & 7)) << 3)]);
      }
      #pragma unroll
      for (int nt = 0; nt < 4; ++nt) {
        int n = 64 * wc + 16 * nt + l15;
        b[nt] = *(const bf16x8*)(w2g + n * 128 + k);
      }
      #pragma unroll
      for (int mt = 0; mt < 2; ++mt)
        #pragma unroll
        for (int nt = 0; nt < 4; ++nt)
          acc2[mt][nt] = __builtin_amdgcn_mfma_f32_16x16x32_bf16(a[mt], b[nt], acc2[mt][nt], 0, 0, 0);
    }

    #pragma unroll
    for (int mt = 0; mt < 2; ++mt)
      #pragma unroll
      for (int r = 0; r < 4; ++r) {
        int row = 32 * wr + 16 * mt + 4 * q + r;
        int2 pr = ((const int2*)adj)[ebase + row];
        int node = clampV(ep ? pr.y : pr.x);
        float* basep = out + (size_t)node * 128 + 64 * wc + l15;
        #pragma unroll
        for (int nt = 0; nt < 4; ++nt)
          unsafeAtomicAdd(basep + 16 * nt, acc2[mt][nt][r]);
      }
  }
}

// ---------------- host launch ----------------------------------------------

extern "C" void kernel_launch(void* const* d_in, const int* in_sizes, int n_in,
                              void* d_out, int out_size, void* d_ws, size_t ws_size,
                              hipStream_t stream) {
  const float* emb = (const float*)d_in[0];
  const int* a0 = (const int*)d_in[1];
  const int* a1 = (const int*)d_in[2];
  const int* a2 = (const int*)d_in[3];
  const int* a3 = (const int*)d_in[4];
  const float* W1 = (const float*)d_in[5];
  const float* W2 = (const float*)d_in[6];
  float* out = (float*)d_out;

  char* ws = (char*)d_ws;
  // main-path layout, no overlays (need 113.1 MB < proven >=116 MB budget):
  bf16* w1t    = (bf16*)(ws);                    //    524,288
  bf16* w2t    = (bf16*)(ws + 524288);           //    262,144
  int*  ids    = (int*) (ws + 786432);           //  5,120,000
  int*  counts = (int*) (ws + 5906432);          //  1,600,000
  int*  cursor = (int*) (ws + 7506432);          //  1,600,000
  int*  offs   = (int*) (ws + 9106432);          //  1,600,256
  int*  bsums  = (int*) (ws + 10706688);         //      4,096
  bf16* Hagg   = (bf16*)(ws + 10710784);         // 102,400,000
  const size_t need_full = 10710784 + 102400000; // 113,110,784
  // embB lives in d_out (12.8 <= 25.6 MB); gemm2 overwrites it at the end.
  bf16* embB = (bf16*)d_out;

  if (ws_size >= need_full) {
    hipMemsetAsync(counts, 0, 3200000, stream);  // counts + cursor
    prep_all_k<<<10286, 256, 0, stream>>>(emb, W1, W2, a0, a1, a2, a3,
                                          embB, w1t, w2t, counts);
    scan_a_k<<<NBLK_SCAN, 256, 0, stream>>>(counts, offs, bsums);
    scan_b_k<<<1, 256, 0, stream>>>(bsums);
    scatter2_k<<<dim3(625, 4), 256, 0, stream>>>(a0, a1, a2, a3, offs, bsums,
                                                 cursor, ids);
    fused_k<<<dim3(NBLK_FUSED, 8), 512, 0, stream>>>(embB, a0, a1, a2, a3,
                                                     w1t, ids, Hagg);
    gemm2_k<<<782, 256, 0, stream>>>(Hagg, w2t, counts, out);
  } else {
    bf16* embB_f = (bf16*)(ws);                  // 12,800,000
    bf16* w1t_f  = (bf16*)(ws + 12800000);       //    524,288
    bf16* w2t_f  = (bf16*)(ws + 13324288);       //    262,144
    prep_emb_k<<<6250, 256, 0, stream>>>(emb, embB_f);
    prep_w_k<<<1536, 256, 0, stream>>>(W1, W2, w1t_f, w2t_f);
    hipMemsetAsync(d_out, 0, (size_t)V_NODES * 128 * sizeof(float), stream);
    edge_k<<<512, 256, 0, stream>>>(embB_f, a0, a1, a2, a3, w1t_f, w2t_f, out);
    relu_k<<<6250, 256, 0, stream>>>(out);
  }
}

// Round 10
// 651.672 us; speedup vs baseline: 1.1657x; 1.1657x over previous
//
#include <hip/hip_runtime.h>

// (V, D, H, L, E) = (50000, 128, 128, 4, 160000)
#define V_NODES 50000
#define NEDGE   160000
#define NSEG    (8 * V_NODES)          // 400000 (g,node) segments
#define NPOS    96                     // owned sorted positions per block
#define NTOT    128                    // computed positions (owned + 32 halo)
#define NBLK_FUSED 1667                // ceil(160000/96)
#define NBLK_SCAN 782                  // ceil(400000/512)

typedef __bf16 bf16;
typedef __attribute__((ext_vector_type(8))) __bf16 bf16x8;
typedef __attribute__((ext_vector_type(4))) __bf16 bf16x4;
typedef __attribute__((ext_vector_type(4))) float  f32x4;

typedef __attribute__((address_space(3))) void       lds_void_t;
typedef __attribute__((address_space(1))) const void gm_void_t;

__device__ __forceinline__ int clampV(int n) {
  unsigned u = (unsigned)n;
  return (int)(u < (unsigned)V_NODES ? u : (unsigned)(V_NODES - 1));
}

__device__ __forceinline__ bf16x8 bzero8() {
  bf16x8 z;
  #pragma unroll
  for (int i = 0; i < 8; ++i) z[i] = (bf16)0.f;
  return z;
}

// ---------------- combined prep: emb->bf16, W1/W2 transpose, histogram -----

__global__ __launch_bounds__(256) void prep_all_k(
    const float* __restrict__ emb, const float* __restrict__ W1,
    const float* __restrict__ W2,
    const int* __restrict__ a0, const int* __restrict__ a1,
    const int* __restrict__ a2, const int* __restrict__ a3,
    bf16* __restrict__ embB, bf16* __restrict__ w1t, bf16* __restrict__ w2t,
    int* __restrict__ counts) {
  const int b = blockIdx.x, t = threadIdx.x;
  if (b < 6250) {
    int i = b * 256 + t;
    float4 v = ((const float4*)emb)[i];
    bf16x4 o = {(bf16)v.x, (bf16)v.y, (bf16)v.z, (bf16)v.w};
    *(bf16x4*)(embB + (size_t)i * 4) = o;
  } else if (b < 7786) {
    int idx = (b - 6250) * 256 + t;
    if (idx < 262144) {
      int n = idx & 127, k = (idx >> 7) & 255, g = idx >> 15;
      w1t[(((g << 7) + n) << 8) + k] = (bf16)W1[idx];
    } else {
      int j = idx - 262144;
      int n = j & 127, k = (j >> 7) & 127, g = j >> 14;
      w2t[(((g << 7) + n) << 7) + k] = (bf16)W2[j];
    }
  } else {
    int j = b - 7786;
    int l = j / 625;
    int e = (j % 625) * 256 + t;
    const int* adj = (l == 0) ? a0 : (l == 1) ? a1 : (l == 2) ? a2 : a3;
    int2 pr = ((const int2*)adj)[e];
    atomicAdd(&counts[(2 * l) * V_NODES + clampV(pr.x)], 1);
    atomicAdd(&counts[(2 * l + 1) * V_NODES + clampV(pr.y)], 1);
  }
}

// ---------------- scan (block-local) + block-sum scan ----------------------

__global__ __launch_bounds__(256) void scan_a_k(const int* __restrict__ counts,
                                                int* __restrict__ offs,
                                                int* __restrict__ bsums) {
  __shared__ int sh[256];
  int t = threadIdx.x, base = blockIdx.x * 512;
  int e0 = base + 2 * t, e1 = e0 + 1;
  int a = (e0 < NSEG) ? counts[e0] : 0;
  int b = (e1 < NSEG) ? counts[e1] : 0;
  int s = a + b;
  sh[t] = s;
  __syncthreads();
  #pragma unroll
  for (int d = 1; d < 256; d <<= 1) {
    int v = (t >= d) ? sh[t - d] : 0;
    __syncthreads();
    sh[t] += v;
    __syncthreads();
  }
  int excl = sh[t] - s;
  if (e0 < NSEG) offs[e0] = excl;
  if (e1 < NSEG) offs[e1] = excl + a;
  if (t == 255) bsums[blockIdx.x] = sh[255];
}

__global__ __launch_bounds__(256) void scan_b_k(int* __restrict__ bsums) {
  __shared__ int sh[256];
  int t = threadIdx.x;
  int v[4]; int s = 0;
  #pragma unroll
  for (int k = 0; k < 4; ++k) {
    int i = t * 4 + k;
    v[k] = (i < NBLK_SCAN) ? bsums[i] : 0;
    s += v[k];
  }
  sh[t] = s;
  __syncthreads();
  #pragma unroll
  for (int d = 1; d < 256; d <<= 1) {
    int x = (t >= d) ? sh[t - d] : 0;
    __syncthreads();
    sh[t] += x;
    __syncthreads();
  }
  int run = sh[t] - s;
  #pragma unroll
  for (int k = 0; k < 4; ++k) {
    int i = t * 4 + k;
    if (i < NBLK_SCAN) bsums[i] = run;
    run += v[k];
  }
}

// ---------------- scatter (scan_c folded in; both endpoints per edge) ------

__global__ __launch_bounds__(256) void scatter2_k(
    const int* __restrict__ a0, const int* __restrict__ a1,
    const int* __restrict__ a2, const int* __restrict__ a3,
    const int* __restrict__ offs, const int* __restrict__ bsums,
    int* __restrict__ cursor, int* __restrict__ ids) {
  int e = blockIdx.x * 256 + threadIdx.x;
  int l = blockIdx.y;
  const int* adj = (l == 0) ? a0 : (l == 1) ? a1 : (l == 2) ? a2 : a3;
  int2 pr = ((const int2*)adj)[e];
  int s0 = (2 * l) * V_NODES + clampV(pr.x);
  int s1 = (2 * l + 1) * V_NODES + clampV(pr.y);
  int p0 = offs[s0] + bsums[s0 >> 9] + atomicAdd(&cursor[s0], 1);
  ids[p0] = e;
  int p1 = offs[s1] + bsums[s1 >> 9] + atomicAdd(&cursor[s1], 1);
  ids[p1] = e;
}

// ---------------- fused GEMM1 + segmented aggregation (v4: DMA staging) ----
// Window = 128 sorted positions (96 owned + 32 halo). raw rows (512 B/pos)
// staged via global_load_lds (16 B/lane, fire-and-forget: no dest VGPRs ->
// removes the serialized-gather pathology of v2/v3) into two 16 KB quarter
// buffers, double-buffered against MFMA. Chunk placement is swizzled at DMA
// time via the per-lane SOURCE address (chunk c of pos p lands at slot
// half*16 + (c ^ (p&15))), so LDS stays contiguous for the DMA while
// ds_read_b128 fragments stay intact. wA register/AGPR-resident as in v2.
// Phase 2 (segment reduce + plain packed-bf16 stores): R8-proven logic.

__global__ __launch_bounds__(512, 4) void fused_k(
    const bf16* __restrict__ embB,
    const int* __restrict__ a0, const int* __restrict__ a1,
    const int* __restrict__ a2, const int* __restrict__ a3,
    const bf16* __restrict__ w1t,
    const int* __restrict__ ids,
    bf16* __restrict__ Hagg) {

  __shared__ __attribute__((aligned(16))) bf16 h_lds[NTOT * 128];   // 32768 B
  __shared__ __attribute__((aligned(16))) bf16 raw_lds[2][32 * 256];// 2x16384
  __shared__ int2 pairs_lds[NTOT];
  __shared__ int  nds_lds[NTOT];
  __shared__ int  starts_lds[NPOS];
  __shared__ int  cnt_lds;
  __shared__ int  prev_lds;

  const int tid = threadIdx.x;
  const int g  = blockIdx.y;
  const int l = g >> 1, ep = g & 1;
  const int* __restrict__ adj = (l == 0) ? a0 : (l == 1) ? a1 : (l == 2) ? a2 : a3;
  const int bl = blockIdx.x;
  const int p0 = g * NEDGE + bl * NPOS;
  const int rem = NEDGE - bl * NPOS;         // >= 64 by grid construction
  const int ntv = rem < NTOT ? rem : NTOT;
  const int npo = rem < NPOS ? rem : NPOS;

  if (tid == 0) {
    cnt_lds = 0;
    prev_lds = (bl > 0) ? clampV(adj[2 * ids[p0 - 1] + ep]) : -2;
  }
  if (tid < NTOT) {
    int2 pr = {0, 0};
    int nd = -1;
    if (tid < ntv) {
      int e = ids[p0 + tid];
      pr = ((const int2*)adj)[e];
      pr.x = clampV(pr.x); pr.y = clampV(pr.y);
      nd = ep ? pr.y : pr.x;
    }
    pairs_lds[tid] = pr;
    nds_lds[tid] = nd;
  }

  const int w = tid >> 6, lane = tid & 63;
  const int dq = w & 3, sub = w >> 2;        // dim-quarter, tile-sub
  const int l15 = lane & 15, q = lane >> 4;

  // W1^T A-fragments in registers: dims dq*32 + mb*16 + l15, k = kb*32+q*8
  bf16x8 wA[2][8];
  const bf16* w1row = w1t + ((size_t)(g * 128 + dq * 32)) * 256;
  #pragma unroll
  for (int mb = 0; mb < 2; ++mb)
    #pragma unroll
    for (int kb = 0; kb < 8; ++kb)
      wA[mb][kb] = *(const bf16x8*)(w1row + (mb * 16 + l15) * 256 + kb * 32 + q * 8);

  __syncthreads();   // A: pairs/nds visible

  // ---- DMA issue: quarter qt (32 positions) into buffer sel ----
  // 16 instrs of 1 KB; wave w issues 2. Lane i: pos = base+ (i>>5),
  // chunk slot i&31 holds chunk ((i&15) ^ (pos&15)) of half (i>>4)&1.
  #define ISSUE(qt, sel)                                                      \
    {                                                                         \
      _Pragma("unroll")                                                       \
      for (int jj = 0; jj < 2; ++jj) {                                        \
        const int ji = w * 2 + jj;                 /* 0..15 */                \
        const int prow = (qt) * 32 + ji * 2;                                  \
        const int pos = prow + (lane >> 5);                                   \
        int2 pr = pairs_lds[pos];                                             \
        const int i5 = lane & 31;                                             \
        const int cs = (i5 & 15) ^ (pos & 15);                                \
        const int node = (i5 < 16) ? pr.x : pr.y;                             \
        const bf16* gp = embB + (size_t)node * 128 + cs * 8;                  \
        bf16* lp = &raw_lds[sel][ji * 2 * 256];                               \
        __builtin_amdgcn_global_load_lds((gm_void_t*)gp, (lds_void_t*)lp,     \
                                         16, 0, 0);                          \
      }                                                                       \
    }

  // ---- compute quarter qt from buffer sel: 1 tile of 16 positions/wave ----
  #define COMP(qt, sel)                                                       \
    {                                                                         \
      const int p = (qt) * 32 + sub * 16 + l15;     /* window position */     \
      const int lp = sub * 16 + l15;                /* buffer row */          \
      const bf16* rrow = &raw_lds[sel][lp * 256];                             \
      f32x4 acc[2] = {};                                                      \
      _Pragma("unroll")                                                       \
      for (int kb = 0; kb < 8; ++kb) {                                        \
        const int kc = kb * 4 + q;                                            \
        const int slot = (kc & 16) + ((kc & 15) ^ (p & 15));                  \
        bf16x8 bfr = *(const bf16x8*)(rrow + slot * 8);                       \
        _Pragma("unroll")                                                     \
        for (int mb = 0; mb < 2; ++mb)                                        \
          acc[mb] = __builtin_amdgcn_mfma_f32_16x16x32_bf16(wA[mb][kb], bfr,  \
                                                            acc[mb], 0, 0, 0);\
      }                                                                       \
      _Pragma("unroll")                                                       \
      for (int mb = 0; mb < 2; ++mb) {                                        \
        const int c = (dq << 3) | (mb << 2) | q;                              \
        bf16x4 o = {(bf16)fmaxf(acc[mb][0], 0.f), (bf16)fmaxf(acc[mb][1], 0.f),\
                    (bf16)fmaxf(acc[mb][2], 0.f), (bf16)fmaxf(acc[mb][3], 0.f)};\
        *(bf16x4*)(&h_lds[p * 128 + ((c ^ (p & 15)) << 2)]) = o;              \
      }                                                                       \
    }

  ISSUE(0, 0)
  ISSUE(1, 1)

  // segment-start detection overlaps the DMA flight
  if (tid < npo) {
    int nd = nds_lds[tid];
    int pv = tid ? nds_lds[tid - 1] : prev_lds;
    if (nd != pv) starts_lds[atomicAdd(&cnt_lds, 1)] = tid;
  }

  __syncthreads();   // B: q0+q1 landed (barrier drains vmcnt), starts done
  COMP(0, 0)
  __syncthreads();   // C: buf0 free
  ISSUE(2, 0)
  COMP(1, 1)
  __syncthreads();   // D: q2 landed, buf1 free
  ISSUE(3, 1)
  COMP(2, 0)
  __syncthreads();   // E: q3 landed
  COMP(3, 1)
  __syncthreads();   // F: h complete

  // ---- phase 2: 8-way wave-parallel segment reduction ----
  const int ncnt = cnt_lds;
  const int ch = lane >> 1;
  const int hw = (lane & 1) << 1;
  bf16* __restrict__ HaggG = Hagg + (size_t)g * V_NODES * 128;
  for (int i = w; i < ncnt; i += 8) {
    int j = starts_lds[i];
    const int node = nds_lds[j];
    float sx = 0.f, sy = 0.f;
    do {
      unsigned u = *(const unsigned*)(&h_lds[j * 128 + ((ch ^ (j & 15)) << 2) + hw]);
      sx += (float)__builtin_bit_cast(bf16, (unsigned short)u);
      sy += (float)__builtin_bit_cast(bf16, (unsigned short)(u >> 16));
      ++j;
    } while (j < ntv && nds_lds[j] == node);
    bf16 plo = (bf16)sx, phi = (bf16)sy;
    unsigned pu = (unsigned)__builtin_bit_cast(unsigned short, plo)
                | ((unsigned)__builtin_bit_cast(unsigned short, phi) << 16);
    *(unsigned*)(HaggG + (size_t)node * 128 + lane * 2) = pu;
  }
  #undef ISSUE
  #undef COMP
}

// ---------------- final GEMM: out = relu(sum_g Hagg_g @ W2_g) --------------
// counts==0 rows are never written by fused_k (hold poison) -> zero-mask.

__global__ __launch_bounds__(256) void gemm2_k(const bf16* __restrict__ Hagg,
                                               const bf16* __restrict__ w2t,
                                               const int* __restrict__ counts,
                                               float* __restrict__ out) {
  const int tid = threadIdx.x, wv = tid >> 6, lane = tid & 63;
  const int l15 = lane & 15, q = lane >> 4;
  const int v0 = blockIdx.x * 64;
  const int vr = v0 + wv * 16 + l15;
  const int vc = vr < V_NODES ? vr : V_NODES - 1;

  f32x4 acc[8] = {};
  for (int g = 0; g < 8; ++g) {
    const int cnt = counts[g * V_NODES + vc];
    const bf16* Ha = Hagg + ((size_t)g * V_NODES + vc) * 128;
    const bf16* Wb = w2t + (size_t)g * 128 * 128;
    #pragma unroll
    for (int kb = 0; kb < 4; ++kb) {
      bf16x8 a = *(const bf16x8*)(Ha + kb * 32 + q * 8);
      if (cnt == 0) a = bzero8();
      #pragma unroll
      for (int nb = 0; nb < 8; ++nb) {
        bf16x8 b = *(const bf16x8*)(Wb + (nb * 16 + l15) * 128 + kb * 32 + q * 8);
        acc[nb] = __builtin_amdgcn_mfma_f32_16x16x32_bf16(a, b, acc[nb], 0, 0, 0);
      }
    }
  }

  const int row = v0 + wv * 16 + q * 4;
  #pragma unroll
  for (int r = 0; r < 4; ++r) {
    if (row + r < V_NODES) {
      #pragma unroll
      for (int nb = 0; nb < 8; ++nb)
        out[(size_t)(row + r) * 128 + nb * 16 + l15] = fmaxf(acc[nb][r], 0.f);
    }
  }
}

// ---------------- fallback path (round-4, proven) --------------------------

__global__ __launch_bounds__(256) void prep_emb_k(const float* __restrict__ in,
                                                  bf16* __restrict__ out) {
  int i = blockIdx.x * 256 + threadIdx.x;
  float4 v = ((const float4*)in)[i];
  bf16x4 o = {(bf16)v.x, (bf16)v.y, (bf16)v.z, (bf16)v.w};
  *(bf16x4*)(out + (size_t)i * 4) = o;
}

__global__ __launch_bounds__(256) void prep_w_k(const float* __restrict__ W1,
                                                const float* __restrict__ W2,
                                                bf16* __restrict__ w1t,
                                                bf16* __restrict__ w2t) {
  int idx = blockIdx.x * 256 + threadIdx.x;
  if (idx < 262144) {
    int n = idx & 127, k = (idx >> 7) & 255, g = idx >> 15;
    w1t[(((g << 7) + n) << 8) + k] = (bf16)W1[idx];
  } else {
    int j = idx - 262144;
    int n = j & 127, k = (j >> 7) & 127, g = j >> 14;
    w2t[(((g << 7) + n) << 7) + k] = (bf16)W2[j];
  }
}

__global__ __launch_bounds__(256) void relu_k(float* __restrict__ out) {
  int i = blockIdx.x * 256 + threadIdx.x;
  float4 v = ((float4*)out)[i];
  v.x = fmaxf(v.x, 0.f); v.y = fmaxf(v.y, 0.f);
  v.z = fmaxf(v.z, 0.f); v.w = fmaxf(v.w, 0.f);
  ((float4*)out)[i] = v;
}

__global__ __launch_bounds__(256) void edge_k(
    const bf16* __restrict__ embB,
    const int* __restrict__ a0, const int* __restrict__ a1,
    const int* __restrict__ a2, const int* __restrict__ a3,
    const bf16* __restrict__ w1t, const bf16* __restrict__ w2t,
    float* __restrict__ out) {

  __shared__ __attribute__((aligned(16))) bf16 w1_lds[128 * 256];
  __shared__ __attribute__((aligned(16))) bf16 h_lds[64 * 128];

  const int tid = threadIdx.x;
  const int g  = blockIdx.x >> 6;
  const int bs = blockIdx.x & 63;
  const int l = g >> 1, ep = g & 1;
  const int* __restrict__ adj = (l == 0) ? a0 : (l == 1) ? a1 : (l == 2) ? a2 : a3;

  {
    const uint4* w1g = (const uint4*)(w1t + (size_t)g * 128 * 256);
    #pragma unroll
    for (int i = 0; i < 16; ++i) {
      int j = i * 256 + tid;
      int n = j >> 5, c = j & 31;
      *(uint4*)(&w1_lds[n * 256 + ((c ^ (n & 7)) << 3)]) = w1g[j];
    }
  }
  __syncthreads();

  const int w    = tid >> 6;
  const int lane = tid & 63;
  const int wr = w >> 1, wc = w & 1;
  const int l15 = lane & 15, q = lane >> 4;
  const bf16* __restrict__ w2g = w2t + (size_t)g * 128 * 128;

  for (int t = bs; t < 2500; t += 64) {
    const int ebase = t * 64;
    int2 pr0 = ((const int2*)adj)[ebase + 32 * wr + l15];
    int2 pr1 = ((const int2*)adj)[ebase + 32 * wr + 16 + l15];
    pr0.x = clampV(pr0.x); pr0.y = clampV(pr0.y);
    pr1.x = clampV(pr1.x); pr1.y = clampV(pr1.y);

    f32x4 acc[2][4] = {};
    #pragma unroll
    for (int kb = 0; kb < 8; ++kb) {
      const int k = kb * 32 + q * 8;
      const int klo = k & 127;
      const int n0 = (kb < 4) ? pr0.x : pr0.y;
      const int n1 = (kb < 4) ? pr1.x : pr1.y;
      bf16x8 a[2], b[4];
      a[0] = *(const bf16x8*)(embB + (size_t)n0 * 128 + klo);
      a[1] = *(const bf16x8*)(embB + (size_t)n1 * 128 + klo);
      const int csw = ((kb << 2) + q);
      #pragma unroll
      for (int nt = 0; nt < 4; ++nt) {
        int n = 64 * wc + 16 * nt + l15;
        b[nt] = *(const bf16x8*)(&w1_lds[n * 256 + ((csw ^ (l15 & 7)) << 3)]);
      }
      #pragma unroll
      for (int mt = 0; mt < 2; ++mt)
        #pragma unroll
        for (int nt = 0; nt < 4; ++nt)
          acc[mt][nt] = __builtin_amdgcn_mfma_f32_16x16x32_bf16(a[mt], b[nt], acc[mt][nt], 0, 0, 0);
    }

    __syncthreads();
    #pragma unroll
    for (int mt = 0; mt < 2; ++mt)
      #pragma unroll
      for (int nt = 0; nt < 4; ++nt)
        #pragma unroll
        for (int r = 0; r < 4; ++r) {
          float v = acc[mt][nt][r];
          v = v > 0.f ? v : 0.f;
          int row = 32 * wr + 16 * mt + 4 * q + r;
          int col = 64 * wc + 16 * nt + l15;
          int c = col >> 3;
          h_lds[row * 128 + (((c ^ (row & 7)) << 3) | (col & 7))] = (bf16)v;
        }
    __syncthreads();

    f32x4 acc2[2][4] = {};
    #pragma unroll
    for (int kb = 0; kb < 4; ++kb) {
      const int k = kb * 32 + q * 8;
      const int csw = (kb << 2) + q;
      bf16x8 a[2], b[4];
      #pragma unroll
      for (int mt = 0; mt < 2; ++mt) {
        int row = 32 * wr + 16 * mt + l15;
        a[mt] = *(const bf16x8*)(&h_lds[row * 128 + ((csw ^ (row & 7)) << 3)]);
      }
      #pragma unroll
      for (int nt = 0; nt < 4; ++nt) {
        int n = 64 * wc + 16 * nt + l15;
        b[nt] = *(const bf16x8*)(w2g + n * 128 + k);
      }
      #pragma unroll
      for (int mt = 0; mt < 2; ++mt)
        #pragma unroll
        for (int nt = 0; nt < 4; ++nt)
          acc2[mt][nt] = __builtin_amdgcn_mfma_f32_16x16x32_bf16(a[mt], b[nt], acc2[mt][nt], 0, 0, 0);
    }

    #pragma unroll
    for (int mt = 0; mt < 2; ++mt)
      #pragma unroll
      for (int r = 0; r < 4; ++r) {
        int row = 32 * wr + 16 * mt + 4 * q + r;
        int2 pr = ((const int2*)adj)[ebase + row];
        int node = clampV(ep ? pr.y : pr.x);
        float* basep = out + (size_t)node * 128 + 64 * wc + l15;
        #pragma unroll
        for (int nt = 0; nt < 4; ++nt)
          unsafeAtomicAdd(basep + 16 * nt, acc2[mt][nt][r]);
      }
  }
}

// ---------------- host launch ----------------------------------------------

extern "C" void kernel_launch(void* const* d_in, const int* in_sizes, int n_in,
                              void* d_out, int out_size, void* d_ws, size_t ws_size,
                              hipStream_t stream) {
  const float* emb = (const float*)d_in[0];
  const int* a0 = (const int*)d_in[1];
  const int* a1 = (const int*)d_in[2];
  const int* a2 = (const int*)d_in[3];
  const int* a3 = (const int*)d_in[4];
  const float* W1 = (const float*)d_in[5];
  const float* W2 = (const float*)d_in[6];
  float* out = (float*)d_out;

  char* ws = (char*)d_ws;
  bf16* w1t    = (bf16*)(ws);                    //    524,288
  bf16* w2t    = (bf16*)(ws + 524288);           //    262,144
  int*  ids    = (int*) (ws + 786432);           //  5,120,000
  int*  counts = (int*) (ws + 5906432);          //  1,600,000
  int*  cursor = (int*) (ws + 7506432);          //  1,600,000
  int*  offs   = (int*) (ws + 9106432);          //  1,600,256
  int*  bsums  = (int*) (ws + 10706688);         //      4,096
  bf16* Hagg   = (bf16*)(ws + 10710784);         // 102,400,000
  const size_t need_full = 10710784 + 102400000; // 113,110,784
  bf16* embB = (bf16*)d_out;   // 12.8 MB in d_out; gemm2 overwrites at end

  if (ws_size >= need_full) {
    hipMemsetAsync(counts, 0, 3200000, stream);  // counts + cursor
    prep_all_k<<<10286, 256, 0, stream>>>(emb, W1, W2, a0, a1, a2, a3,
                                          embB, w1t, w2t, counts);
    scan_a_k<<<NBLK_SCAN, 256, 0, stream>>>(counts, offs, bsums);
    scan_b_k<<<1, 256, 0, stream>>>(bsums);
    scatter2_k<<<dim3(625, 4), 256, 0, stream>>>(a0, a1, a2, a3, offs, bsums,
                                                 cursor, ids);
    fused_k<<<dim3(NBLK_FUSED, 8), 512, 0, stream>>>(embB, a0, a1, a2, a3,
                                                     w1t, ids, Hagg);
    gemm2_k<<<782, 256, 0, stream>>>(Hagg, w2t, counts, out);
  } else {
    bf16* embB_f = (bf16*)(ws);                  // 12,800,000
    bf16* w1t_f  = (bf16*)(ws + 12800000);       //    524,288
    bf16* w2t_f  = (bf16*)(ws + 13324288);       //    262,144
    prep_emb_k<<<6250, 256, 0, stream>>>(emb, embB_f);
    prep_w_k<<<1536, 256, 0, stream>>>(W1, W2, w1t_f, w2t_f);
    hipMemsetAsync(d_out, 0, (size_t)V_NODES * 128 * sizeof(float), stream);
    edge_k<<<512, 256, 0, stream>>>(embB_f, a0, a1, a2, a3, w1t_f, w2t_f, out);
    relu_k<<<6250, 256, 0, stream>>>(out);
  }
}